// Round 4
// baseline (189.361 us; speedup 1.0000x reference)
//
#include <hip/hip_runtime.h>
#include <hip/hip_bf16.h>
#include <math.h>

// Problem constants (AttentionSynapse): B=2, Tq=Tk=2048, E=Eq=Ek=1024, H=16, D=64
#define B_    2
#define TQ    2048
#define TK    2048
#define E_    1024
#define MTOT  4096   // B*TQ

typedef __attribute__((ext_vector_type(8))) short bf16x8;
typedef __attribute__((ext_vector_type(4))) float f32x4;

__device__ __forceinline__ unsigned short f2bf(float x) {
  unsigned int u = __float_as_uint(x);
  u += 0x7fff + ((u >> 16) & 1);      // round-to-nearest-even
  return (unsigned short)(u >> 16);
}

__device__ __forceinline__ void load_lds16(const void* g, void* l) {
  // async global->LDS, 16B/lane; LDS dest = wave-uniform base + lane*16
  __builtin_amdgcn_global_load_lds(
      (const __attribute__((address_space(1))) unsigned int*)g,
      (__attribute__((address_space(3))) unsigned int*)l, 16, 0, 0);
}

#define BARRIER() do { asm volatile("" ::: "memory"); __builtin_amdgcn_s_barrier(); asm volatile("" ::: "memory"); } while (0)
#define WAIT_VM4()   asm volatile("s_waitcnt vmcnt(4)" ::: "memory")
#define WAIT_VM0()   asm volatile("s_waitcnt vmcnt(0)" ::: "memory")
#define WAIT_LGKM0() asm volatile("s_waitcnt lgkmcnt(0)" ::: "memory")

// Stage one half-tile (128 rows x 64 cols bf16) of a [*][1024] row-major source
// into LDS linearly. 512 threads x 2 loads x 16 B. LDS elem = half*8192 + tid*8
// (linear in tid => satisfies gload_lds wave-uniform-base + lane*16).
__device__ __forceinline__ void stage_half(const unsigned short* gsrc, unsigned short* lds,
                                           int tid, int half, int kt) {
  const unsigned short* g = gsrc + (size_t)(half * 128 + (tid >> 3)) * E_ + (size_t)kt * 64 + (tid & 7) * 8;
  unsigned short* l = lds + half * 8192 + tid * 8;
  load_lds16(g, l);
  load_lds16(g + 64 * E_, l + 4096);
}

// ---- fragment reads (LDS [256][64] linear) --------------------------------
#define READ_A(mh)                                                            \
  do {                                                                        \
    _Pragma("unroll") for (int f = 0; f < 4; ++f)                             \
      _Pragma("unroll") for (int ks = 0; ks < 2; ++ks)                        \
        a[f][ks] = *(const bf16x8*)(Ac + ((wm * 128 + (mh) * 64 + f * 16 + li16) * 64 + ks * 32 + hi4 * 8)); \
  } while (0)

#define READ_B(nh)                                                            \
  do {                                                                        \
    _Pragma("unroll") for (int g = 0; g < 2; ++g)                             \
      _Pragma("unroll") for (int ks = 0; ks < 2; ++ks)                        \
        b[nh][g][ks] = *(const bf16x8*)(Bc + ((wn * 64 + (nh) * 32 + g * 16 + li16) * 64 + ks * 32 + hi4 * 8)); \
  } while (0)

#define MFMA_Q(mh, nh)                                                        \
  do {                                                                        \
    __builtin_amdgcn_s_setprio(1);                                            \
    _Pragma("unroll") for (int ks = 0; ks < 2; ++ks)                          \
      _Pragma("unroll") for (int f = 0; f < 4; ++f)                           \
        _Pragma("unroll") for (int g = 0; g < 2; ++g)                         \
          acc[(mh) * 4 + f][(nh) * 2 + g] = __builtin_amdgcn_mfma_f32_16x16x32_bf16( \
              a[f][ks], b[nh][g][ks], acc[(mh) * 4 + f][(nh) * 2 + g], 0, 0, 0); \
    __builtin_amdgcn_s_setprio(0);                                            \
  } while (0)

// 256x256 tile, BK=64, 8 waves (2M x 4N), per-wave C = 128x64, NT=16 K-tiles.
// 4 phases per K-tile; each phase stages exactly one half-tile.
// Stage->region safety (tile t, buf c=t&1):
//   ph1 stages (t+1).A_lo -> As[c^1]   (other buffer: idle since t-1 done)
//   ph2 stages (t+1).A_hi -> As[c^1]
//   ph3 stages (t+2).B_lo -> Bs[c]     (B_lo last read in ph2 by waves wn=0,1)
//   ph4 stages (t+2).B_hi -> Bs[c]     (B_hi last read in ph2 by waves wn=2,3)
// In flight at ph4 wait: (t+1){B_lo,B_hi,A_lo,A_hi} + (t+2){B_lo,B_hi} = 12 loads;
// vmcnt(4) drains the 8 oldest => all of tile t+1 landed; 2 half-tiles remain.
#define GEMM_PIPELINE()                                                       \
  do {                                                                        \
    stage_half(Ag, As[0], tid, 0, 0);                                         \
    stage_half(Ag, As[0], tid, 1, 0);                                         \
    stage_half(Bg, Bs[0], tid, 0, 0);                                         \
    stage_half(Bg, Bs[0], tid, 1, 0);                                         \
    stage_half(Bg, Bs[1], tid, 0, 1);                                         \
    stage_half(Bg, Bs[1], tid, 1, 1);                                         \
    WAIT_VM4();                                                               \
    BARRIER();                                                                \
    for (int t = 0; t < 16; ++t) {                                            \
      const int c = t & 1;                                                    \
      const int nx = (t + 1) & 15;                                            \
      const int nx2 = (t + 2) & 15;                                           \
      unsigned short* Ac = As[c];                                             \
      unsigned short* Bc = Bs[c];                                             \
      /* ph1 */                                                               \
      READ_A(0); READ_B(0);                                                   \
      stage_half(Ag, As[c ^ 1], tid, 0, nx);                                  \
      BARRIER(); WAIT_LGKM0(); MFMA_Q(0, 0); BARRIER();                       \
      /* ph2 */                                                               \
      READ_B(1);                                                              \
      stage_half(Ag, As[c ^ 1], tid, 1, nx);                                  \
      BARRIER(); WAIT_LGKM0(); MFMA_Q(0, 1); BARRIER();                       \
      /* ph3 */                                                               \
      READ_A(1);                                                              \
      stage_half(Bg, Bs[c], tid, 0, nx2);                                     \
      BARRIER(); WAIT_LGKM0(); MFMA_Q(1, 0); BARRIER();                       \
      /* ph4 */                                                               \
      stage_half(Bg, Bs[c], tid, 1, nx2);                                     \
      WAIT_VM4(); BARRIER(); MFMA_Q(1, 1); BARRIER();                         \
    }                                                                         \
  } while (0)

// ---------------------------------------------------------------------------
// prep: bf16-cast gq, gk, WK; scale WQ rows by Wmix[head] then cast.
// ---------------------------------------------------------------------------
__global__ void prep_kernel(const float* __restrict__ gq, const float* __restrict__ gk,
                            const float* __restrict__ WQ, const float* __restrict__ WK,
                            const float* __restrict__ Wmix,
                            unsigned short* __restrict__ gqb, unsigned short* __restrict__ gkb,
                            unsigned short* __restrict__ wqb, unsigned short* __restrict__ wkb) {
  const int NGQ = (B_ * TQ * E_) / 4;   // 1048576 vec4
  const int NW  = (E_ * E_) / 4;        // 262144 vec4
  const int total = 2 * NGQ + 2 * NW;
  for (int idx = blockIdx.x * blockDim.x + threadIdx.x; idx < total;
       idx += gridDim.x * blockDim.x) {
    const float4* src; unsigned short* dst; int local; float scale = 1.0f;
    if (idx < NGQ)            { src = (const float4*)gq; dst = gqb; local = idx; }
    else if (idx < 2 * NGQ)   { src = (const float4*)gk; dst = gkb; local = idx - NGQ; }
    else if (idx < 2*NGQ+NW)  { src = (const float4*)WQ; dst = wqb; local = idx - 2*NGQ;
                                scale = Wmix[local >> 14]; }   // vec4 idx -> row e = local/256, head = e/64
    else                      { src = (const float4*)WK; dst = wkb; local = idx - 2*NGQ - NW; }
    float4 v = src[local];
    ushort4 o;
    o.x = f2bf(v.x * scale); o.y = f2bf(v.y * scale);
    o.z = f2bf(v.z * scale); o.w = f2bf(v.w * scale);
    ((ushort4*)dst)[local] = o;
  }
}

// ---------------------------------------------------------------------------
// Projection GEMM: C[m,n] = sum_k A[m,k]*W[n,k]. 256^2 8-phase pipeline.
// grid = (4 n-tiles, 16 m-tiles, 2 sides)
// ---------------------------------------------------------------------------
__global__ __launch_bounds__(512, 2) void proj_kernel(
    const unsigned short* __restrict__ gqb, const unsigned short* __restrict__ gkb,
    const unsigned short* __restrict__ wqb, const unsigned short* __restrict__ wkb,
    unsigned short* __restrict__ qp, unsigned short* __restrict__ kp) {
  __shared__ __align__(16) unsigned short As[2][16384];
  __shared__ __align__(16) unsigned short Bs[2][16384];
  const int m0 = blockIdx.y * 256, n0 = blockIdx.x * 256;
  const unsigned short* Ag = (blockIdx.z ? gkb : gqb) + (size_t)m0 * E_;
  const unsigned short* Bg = (blockIdx.z ? wkb : wqb) + (size_t)n0 * E_;
  unsigned short* C        = (blockIdx.z ? kp  : qp);
  const int tid = threadIdx.x, wave = tid >> 6, lane = tid & 63;
  const int wm = wave >> 2, wn = wave & 3, li16 = lane & 15, hi4 = lane >> 4;
  f32x4 acc[8][4] = {};
  bf16x8 a[4][2];
  bf16x8 b[2][2][2];
  GEMM_PIPELINE();
  // epilogue: C is [4096][1024] (or [1024][1024] for weights side? no: both sides
  // M rows x 1024 cols, row-major, stride E_)
#pragma unroll
  for (int mr = 0; mr < 8; ++mr)
#pragma unroll
    for (int nr = 0; nr < 4; ++nr)
#pragma unroll
      for (int j = 0; j < 4; ++j) {
        int row = m0 + wm * 128 + mr * 16 + hi4 * 4 + j;
        int col = n0 + wn * 64 + nr * 16 + li16;
        C[(size_t)row * E_ + col] = f2bf(acc[mr][nr][j]);
      }
  WAIT_VM0();   // drain wrapped tail stages before endpgm (LDS is freed at exit)
}

// ---------------------------------------------------------------------------
// Score GEMM + fused partial logsumexp. 256^2 8-phase pipeline.
// grid = (8 k-tiles, 8 q-tiles, 2 batches); partials stride = 8.
// ---------------------------------------------------------------------------
__global__ __launch_bounds__(512, 2) void score_lse_kernel(
    const unsigned short* __restrict__ qp, const unsigned short* __restrict__ kp,
    float2* __restrict__ partials) {
  __shared__ __align__(16) unsigned short As[2][16384];
  __shared__ __align__(16) unsigned short Bs[2][16384];
  __shared__ float redM[4][256];
  __shared__ float redS[4][256];
  const int bb = blockIdx.z;
  const int m0 = blockIdx.y * 256, n0 = blockIdx.x * 256;
  const unsigned short* Ag = qp + (size_t)bb * TQ * E_ + (size_t)m0 * E_;
  const unsigned short* Bg = kp + (size_t)bb * TK * E_ + (size_t)n0 * E_;
  const int tid = threadIdx.x, wave = tid >> 6, lane = tid & 63;
  const int wm = wave >> 2, wn = wave & 3, li16 = lane & 15, hi4 = lane >> 4;
  f32x4 acc[8][4] = {};
  bf16x8 a[4][2];
  bf16x8 b[2][2][2];
  GEMM_PIPELINE();
  // ---- per-row LSE partial over this block's 256 cols ----
  // lane holds rows wm*128 + mr*16 + hi4*4 + j ; cols wn*64 + nr*16 + li16
#pragma unroll
  for (int mr = 0; mr < 8; ++mr) {
#pragma unroll
    for (int j = 0; j < 4; ++j) {
      float m = fmaxf(fmaxf(acc[mr][0][j], acc[mr][1][j]),
                      fmaxf(acc[mr][2][j], acc[mr][3][j]));
#pragma unroll
      for (int msk = 1; msk < 16; msk <<= 1) m = fmaxf(m, __shfl_xor(m, msk, 64));
      float s = 0.f;
#pragma unroll
      for (int nr = 0; nr < 4; ++nr) s += expf(acc[mr][nr][j] - m);
#pragma unroll
      for (int msk = 1; msk < 16; msk <<= 1) s += __shfl_xor(s, msk, 64);
      if (li16 == 0) {
        int row = wm * 128 + mr * 16 + hi4 * 4 + j;   // 0..255, unique per (wm,mr,hi4,j)
        redM[wn][row] = m;
        redS[wn][row] = s;
      }
    }
  }
  __syncthreads();   // also drains the wrapped tail stages (vmcnt 0)
  if (tid < 256) {
    float M = fmaxf(fmaxf(redM[0][tid], redM[1][tid]), fmaxf(redM[2][tid], redM[3][tid]));
    float S = redS[0][tid] * expf(redM[0][tid] - M) + redS[1][tid] * expf(redM[1][tid] - M) +
              redS[2][tid] * expf(redM[2][tid] - M) + redS[3][tid] * expf(redM[3][tid] - M);
    int qrow = bb * TQ + m0 + tid;
    partials[(size_t)qrow * 8 + blockIdx.x] = make_float2(M, S);
  }
}

// ---------------------------------------------------------------------------
// finalize: combine 8 (m,s) partials per q-row -> logsumexp
// ---------------------------------------------------------------------------
__global__ void finalize_kernel(const float2* __restrict__ partials, float* __restrict__ out) {
  int r = blockIdx.x * blockDim.x + threadIdx.x;
  if (r >= MTOT) return;
  const float2* p = partials + (size_t)r * 8;
  float M = p[0].x;
#pragma unroll
  for (int i = 1; i < 8; ++i) M = fmaxf(M, p[i].x);
  float S = 0.f;
#pragma unroll
  for (int i = 0; i < 8; ++i) S += p[i].y * expf(p[i].x - M);
  out[r] = logf(S) + M;
}

// ---------------------------------------------------------------------------
extern "C" void kernel_launch(void* const* d_in, const int* in_sizes, int n_in,
                              void* d_out, int out_size, void* d_ws, size_t ws_size,
                              hipStream_t stream) {
  const float* gq   = (const float*)d_in[0];
  const float* gk   = (const float*)d_in[1];
  const float* WQ   = (const float*)d_in[2];
  const float* WK   = (const float*)d_in[3];
  const float* Wmix = (const float*)d_in[4];
  float* out = (float*)d_out;

  char* ws = (char*)d_ws;
  unsigned short* gqb = (unsigned short*)(ws);                 // 8 MiB
  unsigned short* gkb = (unsigned short*)(ws + 8388608);       // 8 MiB
  unsigned short* wqb = (unsigned short*)(ws + 16777216);      // 2 MiB
  unsigned short* wkb = (unsigned short*)(ws + 18874368);      // 2 MiB
  unsigned short* qp  = (unsigned short*)(ws + 20971520);      // 8 MiB
  unsigned short* kp  = (unsigned short*)(ws + 29360128);      // 8 MiB
  float2* partials    = (float2*)(ws + 37748736);              // 256 KiB

  hipLaunchKernelGGL(prep_kernel, dim3(1024), dim3(256), 0, stream,
                     gq, gk, WQ, WK, Wmix, gqb, gkb, wqb, wkb);
  hipLaunchKernelGGL(proj_kernel, dim3(4, 16, 2), dim3(512), 0, stream,
                     gqb, gkb, wqb, wkb, qp, kp);
  hipLaunchKernelGGL(score_lse_kernel, dim3(8, 8, 2), dim3(512), 0, stream,
                     qp, kp, partials);
  hipLaunchKernelGGL(finalize_kernel, dim3(16), dim3(256), 0, stream,
                     partials, out);
}

// Round 5
// 148.403 us; speedup vs baseline: 1.2760x; 1.2760x over previous
//
#include <hip/hip_runtime.h>
#include <hip/hip_bf16.h>
#include <math.h>

// Problem constants (AttentionSynapse): B=2, Tq=Tk=2048, E=Eq=Ek=1024, H=16, D=64
#define B_    2
#define TQ    2048
#define TK    2048
#define E_    1024
#define MTOT  4096   // B*TQ

typedef __attribute__((ext_vector_type(8))) short bf16x8;
typedef __attribute__((ext_vector_type(4))) float f32x4;

__device__ __forceinline__ unsigned short f2bf(float x) {
  unsigned int u = __float_as_uint(x);
  u += 0x7fff + ((u >> 16) & 1);      // round-to-nearest-even
  return (unsigned short)(u >> 16);
}

__device__ __forceinline__ void load_lds16(const void* g, void* l) {
  // async global->LDS, 16B/lane; LDS dest = wave-uniform base + lane*16
  __builtin_amdgcn_global_load_lds(
      (const __attribute__((address_space(1))) unsigned int*)g,
      (__attribute__((address_space(3))) unsigned int*)l, 16, 0, 0);
}

#define BARRIER() do { asm volatile("" ::: "memory"); __builtin_amdgcn_s_barrier(); asm volatile("" ::: "memory"); } while (0)
#define WAIT_VM4()   asm volatile("s_waitcnt vmcnt(4)" ::: "memory")
#define WAIT_VM0()   asm volatile("s_waitcnt vmcnt(0)" ::: "memory")
#define WAIT_LGKM0() asm volatile("s_waitcnt lgkmcnt(0)" ::: "memory")

// ---------------------------------------------------------------------------
// T2 swizzle: logical (row, byte o in 0..127) lives at LDS byte
//   row*128 + (o ^ ((row&7)<<4)).
// With global_load_lds the LDS write is linear (base + tid*16), so the GLOBAL
// source is pre-permuted with the same (involutive) XOR; the ds_read applies
// the XOR on its address. (rule #21: both-sides-or-neither.)
// ---------------------------------------------------------------------------

// Stage one 64-row x 64-col bf16 chunk (8 KiB, 1 load/thread @512 threads)
// of a [*][1024] row-major source into LDS at elem offset row0*64 (linear).
__device__ __forceinline__ void stage_chunk(const unsigned short* gsrc, unsigned short* lds,
                                            int tid, int row0, int kt) {
  const int r  = tid >> 3;                          // 0..63 chunk-local row
  const int c8 = ((tid & 7) ^ (r & 7)) * 8;         // pre-swizzled col (elems)
  const unsigned short* g = gsrc + (size_t)(row0 + r) * E_ + (size_t)kt * 64 + c8;
  load_lds16(g, lds + row0 * 64 + tid * 8);
}

// Swizzled LDS read address (elems): row in tile, o = byte offset in row
#define LDS_AT(base, row, o) ((const bf16x8*)((base) + (((row) * 128 + ((o) ^ (((row) & 7) << 4))) >> 1)))

// ---- fragment reads -------------------------------------------------------
#define READ_A(mh)                                                            \
  do {                                                                        \
    _Pragma("unroll") for (int f = 0; f < 2; ++f)                             \
      _Pragma("unroll") for (int ks = 0; ks < 2; ++ks)                        \
        a[f][ks] = *LDS_AT(Ac, wm * 64 + (mh) * 32 + f * 16 + li16, ks * 64 + hi4 * 16); \
  } while (0)

#define READ_B(nh)                                                            \
  do {                                                                        \
    _Pragma("unroll") for (int g = 0; g < 2; ++g)                             \
      _Pragma("unroll") for (int ks = 0; ks < 2; ++ks)                        \
        b[nh][g][ks] = *LDS_AT(Bc, wn * 64 + (nh) * 32 + g * 16 + li16, ks * 64 + hi4 * 16); \
  } while (0)

#define MFMA_Q(mh, nh)                                                        \
  do {                                                                        \
    __builtin_amdgcn_s_setprio(1);                                            \
    _Pragma("unroll") for (int ks = 0; ks < 2; ++ks)                          \
      _Pragma("unroll") for (int f = 0; f < 2; ++f)                           \
        _Pragma("unroll") for (int g = 0; g < 2; ++g)                         \
          acc[(mh) * 2 + f][(nh) * 2 + g] = __builtin_amdgcn_mfma_f32_16x16x32_bf16( \
              a[f][ks], b[nh][g][ks], acc[(mh) * 2 + f][(nh) * 2 + g], 0, 0, 0); \
    __builtin_amdgcn_s_setprio(0);                                            \
  } while (0)

// 128x256 tile, BK=64, 8 waves (2M x 4N), per-wave C = 64x64, NT=16 K-tiles.
// Per K-tile: A = 2 chunks, B = 4 chunks (6 loads/thread). 4 phases/tile.
// vmcnt trace (steady state): after prev drain outstanding = B(t+1)x4;
//   ph1 +A0(t+1)=5, ph2 +A1(t+1)=6, ph3 +B01(t+2)=8, ph4 +B23(t+2)=10;
//   vmcnt(4) drains the 6 oldest = all of tile t+1 -> next ph1 reads safe.
// Buffer safety: A(t+1) -> As[c^1] (idle); B(t+2) -> Bs[c], whose last ds_read
//   (READ_B(1)) completed at ph2's lgkmcnt+barrier before ph3 issues stores.
#define GEMM_PIPELINE()                                                       \
  do {                                                                        \
    stage_chunk(Ag, As[0], tid, 0, 0);  stage_chunk(Ag, As[0], tid, 64, 0);   \
    stage_chunk(Bg, Bs[0], tid, 0, 0);  stage_chunk(Bg, Bs[0], tid, 64, 0);   \
    stage_chunk(Bg, Bs[0], tid, 128, 0); stage_chunk(Bg, Bs[0], tid, 192, 0); \
    stage_chunk(Bg, Bs[1], tid, 0, 1);  stage_chunk(Bg, Bs[1], tid, 64, 1);   \
    stage_chunk(Bg, Bs[1], tid, 128, 1); stage_chunk(Bg, Bs[1], tid, 192, 1); \
    WAIT_VM4();                                                               \
    BARRIER();                                                                \
    for (int t = 0; t < 16; ++t) {                                            \
      const int c = t & 1;                                                    \
      const int nx = (t + 1) & 15;                                            \
      const int nx2 = (t + 2) & 15;                                           \
      unsigned short* Ac = As[c];                                             \
      unsigned short* Bc = Bs[c];                                             \
      /* ph1 */                                                               \
      READ_A(0); READ_B(0);                                                   \
      stage_chunk(Ag, As[c ^ 1], tid, 0, nx);                                 \
      BARRIER(); WAIT_LGKM0(); MFMA_Q(0, 0); BARRIER();                       \
      /* ph2 */                                                               \
      READ_B(1);                                                              \
      stage_chunk(Ag, As[c ^ 1], tid, 64, nx);                                \
      BARRIER(); WAIT_LGKM0(); MFMA_Q(0, 1); BARRIER();                       \
      /* ph3 */                                                               \
      READ_A(1);                                                              \
      stage_chunk(Bg, Bs[c], tid, 0, nx2);                                    \
      stage_chunk(Bg, Bs[c], tid, 64, nx2);                                   \
      BARRIER(); WAIT_LGKM0(); MFMA_Q(1, 0); BARRIER();                       \
      /* ph4 */                                                               \
      stage_chunk(Bg, Bs[c], tid, 128, nx2);                                  \
      stage_chunk(Bg, Bs[c], tid, 192, nx2);                                  \
      WAIT_VM4(); BARRIER(); MFMA_Q(1, 1); BARRIER();                         \
    }                                                                         \
  } while (0)

// ---------------------------------------------------------------------------
// prep: bf16-cast gq, gk, WK; scale WQ rows by Wmix[head] then cast.
// ---------------------------------------------------------------------------
__global__ void prep_kernel(const float* __restrict__ gq, const float* __restrict__ gk,
                            const float* __restrict__ WQ, const float* __restrict__ WK,
                            const float* __restrict__ Wmix,
                            unsigned short* __restrict__ gqb, unsigned short* __restrict__ gkb,
                            unsigned short* __restrict__ wqb, unsigned short* __restrict__ wkb) {
  const int NGQ = (B_ * TQ * E_) / 4;   // 1048576 vec4
  const int NW  = (E_ * E_) / 4;        // 262144 vec4
  const int total = 2 * NGQ + 2 * NW;
  for (int idx = blockIdx.x * blockDim.x + threadIdx.x; idx < total;
       idx += gridDim.x * blockDim.x) {
    const float4* src; unsigned short* dst; int local; float scale = 1.0f;
    if (idx < NGQ)            { src = (const float4*)gq; dst = gqb; local = idx; }
    else if (idx < 2 * NGQ)   { src = (const float4*)gk; dst = gkb; local = idx - NGQ; }
    else if (idx < 2*NGQ+NW)  { src = (const float4*)WQ; dst = wqb; local = idx - 2*NGQ;
                                scale = Wmix[local >> 14]; }   // vec4 idx -> row e = local/256, head = e/64
    else                      { src = (const float4*)WK; dst = wkb; local = idx - 2*NGQ - NW; }
    float4 v = src[local];
    ushort4 o;
    o.x = f2bf(v.x * scale); o.y = f2bf(v.y * scale);
    o.z = f2bf(v.z * scale); o.w = f2bf(v.w * scale);
    ((ushort4*)dst)[local] = o;
  }
}

// ---------------------------------------------------------------------------
// Projection GEMM: C[m,n] = sum_k A[m,k]*W[n,k]. 128x256-tile 8-phase pipeline.
// grid = (4 n-tiles, 32 m-tiles, 2 sides) = 256 blocks.
// ---------------------------------------------------------------------------
__global__ __launch_bounds__(512, 2) void proj_kernel(
    const unsigned short* __restrict__ gqb, const unsigned short* __restrict__ gkb,
    const unsigned short* __restrict__ wqb, const unsigned short* __restrict__ wkb,
    unsigned short* __restrict__ qp, unsigned short* __restrict__ kp) {
  __shared__ __align__(16) unsigned short As[2][8192];     // 128 x 64
  __shared__ __align__(16) unsigned short Bs[2][16384];    // 256 x 64
  const int m0 = blockIdx.y * 128, n0 = blockIdx.x * 256;
  const unsigned short* Ag = (blockIdx.z ? gkb : gqb) + (size_t)m0 * E_;
  const unsigned short* Bg = (blockIdx.z ? wkb : wqb) + (size_t)n0 * E_;
  unsigned short* C        = (blockIdx.z ? kp  : qp);
  const int tid = threadIdx.x, wave = tid >> 6, lane = tid & 63;
  const int wm = wave >> 2, wn = wave & 3, li16 = lane & 15, hi4 = lane >> 4;
  f32x4 acc[4][4] = {};
  bf16x8 a[2][2];
  bf16x8 b[2][2][2];
  GEMM_PIPELINE();
#pragma unroll
  for (int mr = 0; mr < 4; ++mr)
#pragma unroll
    for (int nr = 0; nr < 4; ++nr)
#pragma unroll
      for (int j = 0; j < 4; ++j) {
        int row = m0 + wm * 64 + mr * 16 + hi4 * 4 + j;
        int col = n0 + wn * 64 + nr * 16 + li16;
        C[(size_t)row * E_ + col] = f2bf(acc[mr][nr][j]);
      }
  WAIT_VM0();   // drain wrapped tail stages before endpgm
}

// ---------------------------------------------------------------------------
// Score GEMM + fused partial logsumexp. 128x256-tile 8-phase pipeline.
// grid = (8 k-tiles, 16 q-tiles, 2 batches) = 256 blocks; partials stride 8.
// ---------------------------------------------------------------------------
__global__ __launch_bounds__(512, 2) void score_lse_kernel(
    const unsigned short* __restrict__ qp, const unsigned short* __restrict__ kp,
    float2* __restrict__ partials) {
  __shared__ __align__(16) unsigned short As[2][8192];
  __shared__ __align__(16) unsigned short Bs[2][16384];
  __shared__ float redM[4][128];
  __shared__ float redS[4][128];
  const int bb = blockIdx.z;
  const int m0 = blockIdx.y * 128, n0 = blockIdx.x * 256;
  const unsigned short* Ag = qp + (size_t)bb * TQ * E_ + (size_t)m0 * E_;
  const unsigned short* Bg = kp + (size_t)bb * TK * E_ + (size_t)n0 * E_;
  const int tid = threadIdx.x, wave = tid >> 6, lane = tid & 63;
  const int wm = wave >> 2, wn = wave & 3, li16 = lane & 15, hi4 = lane >> 4;
  f32x4 acc[4][4] = {};
  bf16x8 a[2][2];
  bf16x8 b[2][2][2];
  GEMM_PIPELINE();
  // ---- per-row LSE partial over this block's 256 cols ----
  // lane holds rows wm*64 + mr*16 + hi4*4 + j ; cols wn*64 + nr*16 + li16
#pragma unroll
  for (int mr = 0; mr < 4; ++mr) {
#pragma unroll
    for (int j = 0; j < 4; ++j) {
      float m = fmaxf(fmaxf(acc[mr][0][j], acc[mr][1][j]),
                      fmaxf(acc[mr][2][j], acc[mr][3][j]));
#pragma unroll
      for (int msk = 1; msk < 16; msk <<= 1) m = fmaxf(m, __shfl_xor(m, msk, 64));
      float s = 0.f;
#pragma unroll
      for (int nr = 0; nr < 4; ++nr) s += expf(acc[mr][nr][j] - m);
#pragma unroll
      for (int msk = 1; msk < 16; msk <<= 1) s += __shfl_xor(s, msk, 64);
      if (li16 == 0) {
        int row = wm * 64 + mr * 16 + hi4 * 4 + j;   // 0..127 unique per (wm,mr,hi4,j)
        redM[wn][row] = m;
        redS[wn][row] = s;
      }
    }
  }
  __syncthreads();   // also drains wrapped tail stages
  if (tid < 128) {
    float M = fmaxf(fmaxf(redM[0][tid], redM[1][tid]), fmaxf(redM[2][tid], redM[3][tid]));
    float S = redS[0][tid] * expf(redM[0][tid] - M) + redS[1][tid] * expf(redM[1][tid] - M) +
              redS[2][tid] * expf(redM[2][tid] - M) + redS[3][tid] * expf(redM[3][tid] - M);
    int qrow = bb * TQ + m0 + tid;
    partials[(size_t)qrow * 8 + blockIdx.x] = make_float2(M, S);
  }
}

// ---------------------------------------------------------------------------
// finalize: combine 8 (m,s) partials per q-row -> logsumexp
// ---------------------------------------------------------------------------
__global__ void finalize_kernel(const float2* __restrict__ partials, float* __restrict__ out) {
  int r = blockIdx.x * blockDim.x + threadIdx.x;
  if (r >= MTOT) return;
  const float2* p = partials + (size_t)r * 8;
  float M = p[0].x;
#pragma unroll
  for (int i = 1; i < 8; ++i) M = fmaxf(M, p[i].x);
  float S = 0.f;
#pragma unroll
  for (int i = 0; i < 8; ++i) S += p[i].y * expf(p[i].x - M);
  out[r] = logf(S) + M;
}

// ---------------------------------------------------------------------------
extern "C" void kernel_launch(void* const* d_in, const int* in_sizes, int n_in,
                              void* d_out, int out_size, void* d_ws, size_t ws_size,
                              hipStream_t stream) {
  const float* gq   = (const float*)d_in[0];
  const float* gk   = (const float*)d_in[1];
  const float* WQ   = (const float*)d_in[2];
  const float* WK   = (const float*)d_in[3];
  const float* Wmix = (const float*)d_in[4];
  float* out = (float*)d_out;

  char* ws = (char*)d_ws;
  unsigned short* gqb = (unsigned short*)(ws);                 // 8 MiB
  unsigned short* gkb = (unsigned short*)(ws + 8388608);       // 8 MiB
  unsigned short* wqb = (unsigned short*)(ws + 16777216);      // 2 MiB
  unsigned short* wkb = (unsigned short*)(ws + 18874368);      // 2 MiB
  unsigned short* qp  = (unsigned short*)(ws + 20971520);      // 8 MiB
  unsigned short* kp  = (unsigned short*)(ws + 29360128);      // 8 MiB
  float2* partials    = (float2*)(ws + 37748736);              // 256 KiB

  hipLaunchKernelGGL(prep_kernel, dim3(1024), dim3(256), 0, stream,
                     gq, gk, WQ, WK, Wmix, gqb, gkb, wqb, wkb);
  hipLaunchKernelGGL(proj_kernel, dim3(4, 32, 2), dim3(512), 0, stream,
                     gqb, gkb, wqb, wkb, qp, kp);
  hipLaunchKernelGGL(score_lse_kernel, dim3(8, 16, 2), dim3(512), 0, stream,
                     qp, kp, partials);
  hipLaunchKernelGGL(finalize_kernel, dim3(16), dim3(256), 0, stream,
                     partials, out);
}

// Round 6
// 137.852 us; speedup vs baseline: 1.3737x; 1.0765x over previous
//
#include <hip/hip_runtime.h>
#include <hip/hip_bf16.h>
#include <math.h>

// Problem constants (AttentionSynapse): B=2, Tq=Tk=2048, E=Eq=Ek=1024, H=16, D=64
#define B_    2
#define TQ    2048
#define TK    2048
#define E_    1024
#define MTOT  4096   // B*TQ

typedef __attribute__((ext_vector_type(8))) short bf16x8;
typedef __attribute__((ext_vector_type(4))) float f32x4;

__device__ __forceinline__ unsigned short f2bf(float x) {
  unsigned int u = __float_as_uint(x);
  u += 0x7fff + ((u >> 16) & 1);      // round-to-nearest-even
  return (unsigned short)(u >> 16);
}

__device__ __forceinline__ void load_lds16(const void* g, void* l) {
  // async global->LDS, 16B/lane; LDS dest = wave-uniform base + lane*16
  __builtin_amdgcn_global_load_lds(
      (const __attribute__((address_space(1))) unsigned int*)g,
      (__attribute__((address_space(3))) unsigned int*)l, 16, 0, 0);
}

#define BARRIER() do { asm volatile("" ::: "memory"); __builtin_amdgcn_s_barrier(); asm volatile("" ::: "memory"); } while (0)
#define WAIT_VM8()   do { asm volatile("s_waitcnt vmcnt(8)" ::: "memory"); __builtin_amdgcn_sched_barrier(0); } while (0)
#define WAIT_VM0()   do { asm volatile("s_waitcnt vmcnt(0)" ::: "memory"); __builtin_amdgcn_sched_barrier(0); } while (0)
#define WAIT_LGKM0() do { asm volatile("s_waitcnt lgkmcnt(0)" ::: "memory"); __builtin_amdgcn_sched_barrier(0); } while (0)

// ---------------------------------------------------------------------------
// T2 swizzle: logical (row, byte o in 0..127) lives at LDS byte
//   row*128 + (o ^ ((row&7)<<4)).
// LDS write is linear (gload_lds: base + tid*16); the GLOBAL source column is
// pre-permuted with the same involutive XOR; ds_read applies the XOR (rule #21).
// ---------------------------------------------------------------------------

// Stage one 128-row x 64-col bf16 tile (16 KiB) with 256 threads (4 loads/thr)
// from a [*][1024] row-major source into LDS linearly.
__device__ __forceinline__ void stage_tile(const unsigned short* gsrc, unsigned short* lds,
                                           int tid, int kt) {
  const int r  = tid >> 3;                          // 0..31
  const int c8 = ((tid & 7) ^ (r & 7)) * 8;         // pre-swizzled col (elems)
  const unsigned short* g = gsrc + (size_t)r * E_ + (size_t)kt * 64 + c8;
  unsigned short* l = lds + tid * 8;
#pragma unroll
  for (int i = 0; i < 4; ++i)                       // rows r, r+32, r+64, r+96
    load_lds16(g + (size_t)(32 * i) * E_, l + 2048 * i);
}

// Swizzled LDS read address (elems): row in tile, o = byte offset in row
#define LDS_AT(base, row, o) ((const bf16x8*)((base) + (((row) * 128 + ((o) ^ (((row) & 7) << 4))) >> 1)))

#define READ_ALL()                                                            \
  do {                                                                        \
    _Pragma("unroll") for (int f = 0; f < 4; ++f)                             \
      _Pragma("unroll") for (int ks = 0; ks < 2; ++ks) {                      \
        a[f][ks] = *LDS_AT(Ac, wm * 64 + f * 16 + li16, ks * 64 + hi4 * 16);  \
        b[f][ks] = *LDS_AT(Bc, wn * 64 + f * 16 + li16, ks * 64 + hi4 * 16);  \
      }                                                                       \
  } while (0)

#define MFMA_ALL()                                                            \
  do {                                                                        \
    __builtin_amdgcn_s_setprio(1);                                            \
    _Pragma("unroll") for (int ks = 0; ks < 2; ++ks)                          \
      _Pragma("unroll") for (int f = 0; f < 4; ++f)                           \
        _Pragma("unroll") for (int g = 0; g < 4; ++g)                         \
          acc[f][g] = __builtin_amdgcn_mfma_f32_16x16x32_bf16(                \
              a[f][ks], b[g][ks], acc[f][g], 0, 0, 0);                        \
    __builtin_amdgcn_s_setprio(0);                                            \
  } while (0)

// 128x128 tile, BK=64, 4 waves (2M x 2N), per-wave C = 64x64, NT=16 K-tiles.
// Per K-tile, per thread: 16 ds_read_b128, 8 global_load_lds, 32 MFMA,
// exactly 2 barriers. Prefetch distance 2; vmcnt(8) keeps tile t+2 in flight.
// Region safety: stage(t+2) targets buf c AFTER lgkm0+barrier proved all
// waves retired their reads of buf c this tile.
#define GEMM_PIPELINE()                                                       \
  do {                                                                        \
    stage_tile(Ag, As[0], tid, 0); stage_tile(Bg, Bs[0], tid, 0);             \
    stage_tile(Ag, As[1], tid, 1); stage_tile(Bg, Bs[1], tid, 1);             \
    WAIT_VM8();                                                               \
    BARRIER();                                                                \
    for (int t = 0; t < 16; ++t) {                                            \
      const int c = t & 1;                                                    \
      unsigned short* Ac = As[c];                                             \
      unsigned short* Bc = Bs[c];                                             \
      READ_ALL();                                                             \
      WAIT_LGKM0();          /* my 16 reads retired (regs valid) */           \
      BARRIER();             /* all waves done reading buf c */               \
      stage_tile(Ag, As[c], tid, (t + 2) & 15);                               \
      stage_tile(Bg, Bs[c], tid, (t + 2) & 15);                               \
      MFMA_ALL();            /* 32 MFMA hide the 8 loads' flight */           \
      WAIT_VM8();            /* tile t+1 landed; t+2's 8 in flight */         \
      BARRIER();                                                              \
    }                                                                         \
  } while (0)

// ---------------------------------------------------------------------------
// prep: bf16-cast gq, gk, WK; scale WQ rows by Wmix[head] then cast.
// ---------------------------------------------------------------------------
__global__ void prep_kernel(const float* __restrict__ gq, const float* __restrict__ gk,
                            const float* __restrict__ WQ, const float* __restrict__ WK,
                            const float* __restrict__ Wmix,
                            unsigned short* __restrict__ gqb, unsigned short* __restrict__ gkb,
                            unsigned short* __restrict__ wqb, unsigned short* __restrict__ wkb) {
  const int NGQ = (B_ * TQ * E_) / 4;   // 1048576 vec4
  const int NW  = (E_ * E_) / 4;        // 262144 vec4
  const int total = 2 * NGQ + 2 * NW;
  for (int idx = blockIdx.x * blockDim.x + threadIdx.x; idx < total;
       idx += gridDim.x * blockDim.x) {
    const float4* src; unsigned short* dst; int local; float scale = 1.0f;
    if (idx < NGQ)            { src = (const float4*)gq; dst = gqb; local = idx; }
    else if (idx < 2 * NGQ)   { src = (const float4*)gk; dst = gkb; local = idx - NGQ; }
    else if (idx < 2*NGQ+NW)  { src = (const float4*)WQ; dst = wqb; local = idx - 2*NGQ;
                                scale = Wmix[local >> 14]; }   // vec4 idx -> row e = local/256, head = e/64
    else                      { src = (const float4*)WK; dst = wkb; local = idx - 2*NGQ - NW; }
    float4 v = src[local];
    ushort4 o;
    o.x = f2bf(v.x * scale); o.y = f2bf(v.y * scale);
    o.z = f2bf(v.z * scale); o.w = f2bf(v.w * scale);
    ((ushort4*)dst)[local] = o;
  }
}

// ---------------------------------------------------------------------------
// Projection GEMM: C[m,n] = sum_k A[m,k]*W[n,k]. 128x128-tile, 4 waves,
// 2 blocks/CU. grid = (8 n-tiles, 32 m-tiles, 2 sides) = 512 blocks.
// ---------------------------------------------------------------------------
__global__ __launch_bounds__(256, 2) void proj_kernel(
    const unsigned short* __restrict__ gqb, const unsigned short* __restrict__ gkb,
    const unsigned short* __restrict__ wqb, const unsigned short* __restrict__ wkb,
    unsigned short* __restrict__ qp, unsigned short* __restrict__ kp) {
  __shared__ __align__(16) unsigned short As[2][8192];   // 128 x 64
  __shared__ __align__(16) unsigned short Bs[2][8192];   // 128 x 64
  const int m0 = blockIdx.y * 128, n0 = blockIdx.x * 128;
  const unsigned short* Ag = (blockIdx.z ? gkb : gqb) + (size_t)m0 * E_;
  const unsigned short* Bg = (blockIdx.z ? wkb : wqb) + (size_t)n0 * E_;
  unsigned short* C        = (blockIdx.z ? kp  : qp);
  const int tid = threadIdx.x, wave = tid >> 6, lane = tid & 63;
  const int wm = wave >> 1, wn = wave & 1, li16 = lane & 15, hi4 = lane >> 4;
  f32x4 acc[4][4] = {};
  bf16x8 a[4][2];
  bf16x8 b[4][2];
  GEMM_PIPELINE();
#pragma unroll
  for (int f = 0; f < 4; ++f)
#pragma unroll
    for (int g = 0; g < 4; ++g)
#pragma unroll
      for (int j = 0; j < 4; ++j) {
        int row = m0 + wm * 64 + f * 16 + hi4 * 4 + j;
        int col = n0 + wn * 64 + g * 16 + li16;
        C[(size_t)row * E_ + col] = f2bf(acc[f][g][j]);
      }
  WAIT_VM0();   // drain wrapped tail stages before endpgm
}

// ---------------------------------------------------------------------------
// Score GEMM + fused partial logsumexp. 128x128-tile, 4 waves, 2 blocks/CU.
// grid = (16 k-tiles, 16 q-tiles, 2 batches) = 512 blocks; partials stride 16.
// ---------------------------------------------------------------------------
__global__ __launch_bounds__(256, 2) void score_lse_kernel(
    const unsigned short* __restrict__ qp, const unsigned short* __restrict__ kp,
    float2* __restrict__ partials) {
  __shared__ __align__(16) unsigned short As[2][8192];
  __shared__ __align__(16) unsigned short Bs[2][8192];
  __shared__ float redM[2][128];
  __shared__ float redS[2][128];
  const int bb = blockIdx.z;
  const int m0 = blockIdx.y * 128, n0 = blockIdx.x * 128;
  const unsigned short* Ag = qp + (size_t)bb * TQ * E_ + (size_t)m0 * E_;
  const unsigned short* Bg = kp + (size_t)bb * TK * E_ + (size_t)n0 * E_;
  const int tid = threadIdx.x, wave = tid >> 6, lane = tid & 63;
  const int wm = wave >> 1, wn = wave & 1, li16 = lane & 15, hi4 = lane >> 4;
  f32x4 acc[4][4] = {};
  bf16x8 a[4][2];
  bf16x8 b[4][2];
  GEMM_PIPELINE();
  // ---- per-row LSE partial over this block's 128 cols ----
  // lane holds rows wm*64 + f*16 + hi4*4 + j ; cols wn*64 + g*16 + li16
#pragma unroll
  for (int f = 0; f < 4; ++f) {
#pragma unroll
    for (int j = 0; j < 4; ++j) {
      float m = fmaxf(fmaxf(acc[f][0][j], acc[f][1][j]),
                      fmaxf(acc[f][2][j], acc[f][3][j]));
#pragma unroll
      for (int msk = 1; msk < 16; msk <<= 1) m = fmaxf(m, __shfl_xor(m, msk, 64));
      float s = 0.f;
#pragma unroll
      for (int g = 0; g < 4; ++g) s += expf(acc[f][g][j] - m);
#pragma unroll
      for (int msk = 1; msk < 16; msk <<= 1) s += __shfl_xor(s, msk, 64);
      if (li16 == 0) {
        int row = wm * 64 + f * 16 + hi4 * 4 + j;   // 0..127 unique per (wm,f,hi4,j)
        redM[wn][row] = m;
        redS[wn][row] = s;
      }
    }
  }
  __syncthreads();   // compiler emits vmcnt(0)+lgkmcnt(0) drain here
  if (tid < 128) {
    float mA = redM[0][tid], mB = redM[1][tid];
    float M = fmaxf(mA, mB);
    float S = redS[0][tid] * expf(mA - M) + redS[1][tid] * expf(mB - M);
    int qrow = bb * TQ + m0 + tid;
    partials[(size_t)qrow * 16 + blockIdx.x] = make_float2(M, S);
  }
}

// ---------------------------------------------------------------------------
// finalize: combine 16 (m,s) partials per q-row -> logsumexp
// ---------------------------------------------------------------------------
__global__ void finalize_kernel(const float2* __restrict__ partials, float* __restrict__ out) {
  int r = blockIdx.x * blockDim.x + threadIdx.x;
  if (r >= MTOT) return;
  const float2* p = partials + (size_t)r * 16;
  float M = p[0].x;
#pragma unroll
  for (int i = 1; i < 16; ++i) M = fmaxf(M, p[i].x);
  float S = 0.f;
#pragma unroll
  for (int i = 0; i < 16; ++i) S += p[i].y * expf(p[i].x - M);
  out[r] = logf(S) + M;
}

// ---------------------------------------------------------------------------
extern "C" void kernel_launch(void* const* d_in, const int* in_sizes, int n_in,
                              void* d_out, int out_size, void* d_ws, size_t ws_size,
                              hipStream_t stream) {
  const float* gq   = (const float*)d_in[0];
  const float* gk   = (const float*)d_in[1];
  const float* WQ   = (const float*)d_in[2];
  const float* WK   = (const float*)d_in[3];
  const float* Wmix = (const float*)d_in[4];
  float* out = (float*)d_out;

  char* ws = (char*)d_ws;
  unsigned short* gqb = (unsigned short*)(ws);                 // 8 MiB
  unsigned short* gkb = (unsigned short*)(ws + 8388608);       // 8 MiB
  unsigned short* wqb = (unsigned short*)(ws + 16777216);      // 2 MiB
  unsigned short* wkb = (unsigned short*)(ws + 18874368);      // 2 MiB
  unsigned short* qp  = (unsigned short*)(ws + 20971520);      // 8 MiB
  unsigned short* kp  = (unsigned short*)(ws + 29360128);      // 8 MiB
  float2* partials    = (float2*)(ws + 37748736);              // 512 KiB

  hipLaunchKernelGGL(prep_kernel, dim3(1024), dim3(256), 0, stream,
                     gq, gk, WQ, WK, Wmix, gqb, gkb, wqb, wkb);
  hipLaunchKernelGGL(proj_kernel, dim3(8, 32, 2), dim3(256), 0, stream,
                     gqb, gkb, wqb, wkb, qp, kp);
  hipLaunchKernelGGL(score_lse_kernel, dim3(16, 16, 2), dim3(256), 0, stream,
                     qp, kp, partials);
  hipLaunchKernelGGL(finalize_kernel, dim3(16), dim3(256), 0, stream,
                     partials, out);
}